// Round 5
// baseline (1791.699 us; speedup 1.0000x reference)
//
#include <hip/hip_runtime.h>
#include <cstdint>
#include <cstddef>
#include <math.h>

#define T_SEQ  1024
#define DMODEL 1024
#define NHEAD  16
#define HDIM   64
#define NEXP   8
#define IDIM   4096
#define NTOK   2048
#define NSLOT  4096

typedef short bf16x8 __attribute__((ext_vector_type(8)));
typedef short s16x4  __attribute__((ext_vector_type(4)));
typedef float floatx4 __attribute__((ext_vector_type(4)));

__device__ __forceinline__ float bf2f(short s) {
  return __uint_as_float(((unsigned)(unsigned short)s) << 16);
}
__device__ __forceinline__ short f2bf(float f) {
  unsigned u = __float_as_uint(f);
  unsigned r = (u + 0x7FFFu + ((u >> 16) & 1u)) >> 16;
  return (short)r;
}

// ---------------- RMSNorm: fp32 in -> fp32 out ----------------
__global__ __launch_bounds__(256) void rmsnorm_f32_kernel(
    const float* __restrict__ x, const float* __restrict__ w, float* __restrict__ out) {
  int row = blockIdx.x, tid = threadIdx.x;
  const floatx4* xr = (const floatx4*)(x + (size_t)row * DMODEL);
  floatx4 v = xr[tid];
  float ss = v[0]*v[0] + v[1]*v[1] + v[2]*v[2] + v[3]*v[3];
  #pragma unroll
  for (int off = 32; off > 0; off >>= 1) ss += __shfl_xor(ss, off);
  __shared__ float wsum[4];
  int wid = tid >> 6;
  if ((tid & 63) == 0) wsum[wid] = ss;
  __syncthreads();
  float tot = wsum[0] + wsum[1] + wsum[2] + wsum[3];
  float r = rsqrtf(tot * (1.0f / DMODEL) + 1e-6f);
  floatx4 wv = ((const floatx4*)w)[tid];
  floatx4 o;
  o[0] = v[0]*r*wv[0]; o[1] = v[1]*r*wv[1];
  o[2] = v[2]*r*wv[2]; o[3] = v[3]*r*wv[3];
  ((floatx4*)(out + (size_t)row * DMODEL))[tid] = o;
}

// ---------------- RMSNorm: fp32 in -> bf16 out (for MoE input) ----------------
__global__ __launch_bounds__(256) void rmsnorm_bf16_kernel(
    const float* __restrict__ x, const float* __restrict__ w, short* __restrict__ out) {
  int row = blockIdx.x, tid = threadIdx.x;
  const floatx4* xr = (const floatx4*)(x + (size_t)row * DMODEL);
  floatx4 v = xr[tid];
  float ss = v[0]*v[0] + v[1]*v[1] + v[2]*v[2] + v[3]*v[3];
  #pragma unroll
  for (int off = 32; off > 0; off >>= 1) ss += __shfl_xor(ss, off);
  __shared__ float wsum[4];
  int wid = tid >> 6;
  if ((tid & 63) == 0) wsum[wid] = ss;
  __syncthreads();
  float tot = wsum[0] + wsum[1] + wsum[2] + wsum[3];
  float r = rsqrtf(tot * (1.0f / DMODEL) + 1e-6f);
  floatx4 wv = ((const floatx4*)w)[tid];
  s16x4 o;
  o[0] = f2bf(v[0]*r*wv[0]); o[1] = f2bf(v[1]*r*wv[1]);
  o[2] = f2bf(v[2]*r*wv[2]); o[3] = f2bf(v[3]*r*wv[3]);
  *(s16x4*)(out + (size_t)row * DMODEL + tid*4) = o;
}

// ---------------- fp32 vector-ALU GEMM: C = A(MxK) @ W(NxK)^T + bias [+resid] ----------------
// Tile 128(M) x 64(N), K-step 16. 256 threads, each computes 8x4.
template<int RESID>
__global__ __launch_bounds__(256) void gemm_f32(
    const float* __restrict__ A, const float* __restrict__ W,
    const float* __restrict__ bias, const float* __restrict__ resid,
    float* __restrict__ C, int N, int K) {
  __shared__ float Ast[16][132];   // [k][m]
  __shared__ float Bst[16][68];    // [k][n]
  int tid = threadIdx.x;
  int m0 = blockIdx.y * 128, n0 = blockIdx.x * 64;
  int ar = tid >> 1, ac = (tid & 1) * 8;     // A: row, k-offset (8 floats)
  int br = tid >> 2, bc = (tid & 3) * 4;     // B: row, k-offset (4 floats)
  int ty = tid >> 4, tx = tid & 15;          // compute: ty->M (8 rows), tx->N (4 cols)

  float acc[8][4];
  #pragma unroll
  for (int i = 0; i < 8; i++)
    #pragma unroll
    for (int j = 0; j < 4; j++) acc[i][j] = 0.f;

  const float* Ap = A + (size_t)(m0 + ar) * K;
  const float* Wp = W + (size_t)(n0 + br) * K;

  for (int kk = 0; kk < K; kk += 16) {
    floatx4 a0 = *(const floatx4*)(Ap + kk + ac);
    floatx4 a1 = *(const floatx4*)(Ap + kk + ac + 4);
    floatx4 b0 = *(const floatx4*)(Wp + kk + bc);
    __syncthreads();
    #pragma unroll
    for (int j = 0; j < 4; j++) {
      Ast[ac + j][ar]     = a0[j];
      Ast[ac + 4 + j][ar] = a1[j];
      Bst[bc + j][br]     = b0[j];
    }
    __syncthreads();
    #pragma unroll
    for (int k = 0; k < 16; k++) {
      floatx4 av0 = *(const floatx4*)(&Ast[k][ty*8]);
      floatx4 av1 = *(const floatx4*)(&Ast[k][ty*8 + 4]);
      floatx4 bv  = *(const floatx4*)(&Bst[k][tx*4]);
      #pragma unroll
      for (int i = 0; i < 4; i++)
        #pragma unroll
        for (int j = 0; j < 4; j++) {
          acc[i][j]   = fmaf(av0[i], bv[j], acc[i][j]);
          acc[4+i][j] = fmaf(av1[i], bv[j], acc[4+i][j]);
        }
    }
  }
  #pragma unroll
  for (int i = 0; i < 8; i++) {
    int m = m0 + ty*8 + i;
    #pragma unroll
    for (int j = 0; j < 4; j++) {
      int n = n0 + tx*4 + j;
      float v = acc[i][j] + bias[n];
      if (RESID) v += resid[(size_t)m * N + n];
      C[(size_t)m * N + n] = v;
    }
  }
}

// ---------------- RoPE table (fp64 generation) ----------------
__global__ void rope_table_kernel(float* __restrict__ cost, float* __restrict__ sint) {
  int t = blockIdx.x, d = threadIdx.x;  // block 32
  double theta = pow(10000.0, -(double)d / 32.0);
  double f = (double)t * theta;
  cost[t*32 + d] = (float)cos(f);
  sint[t*32 + d] = (float)sin(f);
}

// ---------------- RoPE + transpose to [B][H][T][hd], fp32 ----------------
__global__ __launch_bounds__(256) void rope_kernel(
    const float* __restrict__ qkv, const float* __restrict__ cost, const float* __restrict__ sint,
    float* __restrict__ qr, float* __restrict__ kr, float* __restrict__ vr) {
  int wid = threadIdx.x >> 6, lane = threadIdx.x & 63;
  int idx = blockIdx.x * 4 + wid;        // over NTOK*NHEAD
  int h = idx & 15, n = idx >> 4;
  int t = n & (T_SEQ - 1), b = n >> 10;
  const float* base = qkv + (size_t)n * 3072 + h * 192;
  int d2 = lane & 31;
  float c = cost[t*32 + d2], s = sint[t*32 + d2];
  float q1 = base[d2],      q2 = base[d2 + 32];
  float k1 = base[64 + d2], k2 = base[96 + d2];
  float qo = (lane < 32) ? (q1*c - q2*s) : (q1*s + q2*c);
  float ko = (lane < 32) ? (k1*c - k2*s) : (k1*s + k2*c);
  size_t orow = ((size_t)(b*NHEAD + h) * T_SEQ + t) * HDIM;
  qr[orow + lane] = qo;
  kr[orow + lane] = ko;
  vr[orow + lane] = base[128 + lane];
}

// ---------------- causal attention, fp32, 1 wave per q-row, two-pass softmax ----------------
__global__ __launch_bounds__(256) void attn_kernel(
    const float* __restrict__ qr, const float* __restrict__ kr,
    const float* __restrict__ vr, float* __restrict__ attno) {
  __shared__ float red[4][64][17];
  int wid = threadIdx.x >> 6, lane = threadIdx.x & 63;
  int row = blockIdx.x * 4 + wid;     // (b*H+h)*T + q
  int q_idx = row & (T_SEQ - 1);
  int bh = row >> 10;
  const floatx4* Qp = (const floatx4*)(qr + (size_t)row * HDIM);
  float qreg[64];
  #pragma unroll
  for (int u = 0; u < 16; u++) {
    floatx4 v = Qp[u];
    #pragma unroll
    for (int j = 0; j < 4; j++) qreg[u*4 + j] = v[j];
  }
  const float* Kb = kr + (size_t)bh * T_SEQ * HDIM;
  const float* Vb = vr + (size_t)bh * T_SEQ * HDIM;
  int nk = q_idx + 1;
  const float scale = 0.03125f;   // D^-0.5 with D=1024 (reference uses full model dim)
  float sreg[16];
  float mx = -1e30f;
  #pragma unroll
  for (int j = 0; j < 16; j++) {
    sreg[j] = -1e30f;
    if (j*64 >= nk) continue;
    int ki = j*64 + lane;
    if (ki < nk) {
      const floatx4* kp = (const floatx4*)(Kb + (size_t)ki * HDIM);
      float acc = 0.f;
      #pragma unroll
      for (int u = 0; u < 16; u++) {
        floatx4 kv = kp[u];
        #pragma unroll
        for (int jj = 0; jj < 4; jj++) acc = fmaf(qreg[u*4 + jj], kv[jj], acc);
      }
      float d = acc * scale;
      sreg[j] = d;
      mx = fmaxf(mx, d);
    }
  }
  #pragma unroll
  for (int off = 32; off > 0; off >>= 1) mx = fmaxf(mx, __shfl_xor(mx, off));
  float l = 0.f;
  float o[64];
  #pragma unroll
  for (int d = 0; d < 64; d++) o[d] = 0.f;
  #pragma unroll
  for (int j = 0; j < 16; j++) {
    if (j*64 >= nk) continue;
    if (sreg[j] > -1e29f) {
      float p = __expf(sreg[j] - mx);
      l += p;
      int ki = j*64 + lane;
      const floatx4* vp = (const floatx4*)(Vb + (size_t)ki * HDIM);
      #pragma unroll
      for (int u = 0; u < 16; u++) {
        floatx4 vv = vp[u];
        #pragma unroll
        for (int jj = 0; jj < 4; jj++) o[u*4 + jj] = fmaf(p, vv[jj], o[u*4 + jj]);
      }
    }
  }
  #pragma unroll
  for (int off = 32; off > 0; off >>= 1) l += __shfl_xor(l, off);
  float inv = 1.0f / l;
  int b = bh >> 4, h = bh & 15;
  float* orow = attno + ((size_t)(b*T_SEQ + q_idx)) * DMODEL + h*HDIM;
  int r0 = (lane >> 4) * 16, col = lane & 15;
  #pragma unroll
  for (int c = 0; c < 4; c++) {
    #pragma unroll
    for (int i = 0; i < 16; i++) red[wid][lane][i] = o[c*16 + i] * inv;
    __syncthreads();
    float acc = 0.f;
    #pragma unroll
    for (int i = 0; i < 16; i++) acc += red[wid][r0 + i][col];
    acc += __shfl_xor(acc, 16);
    acc += __shfl_xor(acc, 32);
    if (lane < 16) orow[c*16 + lane] = acc;
    __syncthreads();
  }
}

// ---------------- gate: FULL FP64 path (inline rmsnorm of fp32-accurate h1) ----------------
__global__ __launch_bounds__(64) void gate_kernel(
    const float* __restrict__ h1, const float* __restrict__ lnw, const float* __restrict__ gw,
    float* __restrict__ probs, int* __restrict__ pair, float* __restrict__ gpair,
    int* __restrict__ counts) {
  int n = blockIdx.x, lane = threadIdx.x;
  const float* xp = h1 + (size_t)n * DMODEL + lane*16;
  float xv[16];
  double ss = 0.0;
  #pragma unroll
  for (int j = 0; j < 16; j++) { xv[j] = xp[j]; ss += (double)xv[j] * (double)xv[j]; }
  #pragma unroll
  for (int off = 32; off > 0; off >>= 1) ss += __shfl_xor(ss, off);
  double r = 1.0 / sqrt(ss * (1.0 / DMODEL) + 1e-6);
  const float* wp = lnw + lane*16;
  double xf[16];
  #pragma unroll
  for (int j = 0; j < 16; j++) xf[j] = (double)xv[j] * r * (double)wp[j];
  double logit[8];
  #pragma unroll
  for (int e = 0; e < 8; e++) {
    const float* g = gw + e*DMODEL + lane*16;
    double acc = 0.0;
    #pragma unroll
    for (int j = 0; j < 16; j++) acc += xf[j] * (double)g[j];
    logit[e] = acc;
  }
  #pragma unroll
  for (int e = 0; e < 8; e++)
    #pragma unroll
    for (int off = 32; off > 0; off >>= 1) logit[e] += __shfl_xor(logit[e], off);
  double mxl = logit[0];
  #pragma unroll
  for (int e = 1; e < 8; e++) mxl = fmax(mxl, logit[e]);
  double p[8], Z = 0.0;
  #pragma unroll
  for (int e = 0; e < 8; e++) { p[e] = exp(logit[e] - mxl); Z += p[e]; }
  double invZ = 1.0 / Z;
  #pragma unroll
  for (int e = 0; e < 8; e++) p[e] *= invZ;
  int e0 = 0; double b0 = p[0];
  #pragma unroll
  for (int e = 1; e < 8; e++) if (p[e] > b0) { b0 = p[e]; e0 = e; }
  int e1 = -1; double b1 = -1.0;
  #pragma unroll
  for (int e = 0; e < 8; e++) if (e != e0 && p[e] > b1) { b1 = p[e]; e1 = e; }
  if (lane == 0) {
    #pragma unroll
    for (int e = 0; e < 8; e++) probs[n*8 + e] = (float)p[e];
    pair[2*n] = e0; pair[2*n+1] = e1;
    gpair[2*n] = (float)b0; gpair[2*n+1] = (float)b1;
    atomicAdd(&counts[e0], 1);
    atomicAdd(&counts[e1], 1);
  }
}

__global__ void offsets_kernel(const int* __restrict__ counts, int* __restrict__ off,
                               int* __restrict__ cursor) {
  if (threadIdx.x == 0) {
    int a = 0;
    for (int e = 0; e < 8; e++) { off[e] = a; cursor[e] = a; a += counts[e]; }
    off[8] = a;
  }
}

__global__ __launch_bounds__(256) void scatter_kernel(
    const int* __restrict__ pair, const float* __restrict__ gpair, int* __restrict__ cursor,
    int* __restrict__ tok_of_slot, float* __restrict__ gate_of_slot, int* __restrict__ slot_of_tok) {
  int n = blockIdx.x * 256 + threadIdx.x;
  int e0 = pair[2*n], e1 = pair[2*n+1];
  int s0 = atomicAdd(&cursor[e0], 1);
  tok_of_slot[s0] = n; gate_of_slot[s0] = gpair[2*n];   slot_of_tok[2*n] = s0;
  int s1 = atomicAdd(&cursor[e1], 1);
  tok_of_slot[s1] = n; gate_of_slot[s1] = gpair[2*n+1]; slot_of_tok[2*n+1] = s1;
}

__global__ __launch_bounds__(256) void aux_kernel(
    const float* __restrict__ probs, const int* __restrict__ counts, float* __restrict__ outaux) {
  __shared__ double sm[256];
  int t = threadIdx.x;
  int e = t & 7, base = t >> 3;
  double acc = 0.0;
  for (int n = base; n < NTOK; n += 32) acc += (double)probs[n*8 + e];
  sm[t] = acc;
  __syncthreads();
  if (t < 8) {
    double s = 0.0;
    for (int g = 0; g < 32; g++) s += sm[g*8 + t];
    sm[t] = s;
  }
  __syncthreads();
  if (t == 0) {
    double aux = 0.0;
    for (int ee = 0; ee < 8; ee++)
      aux += ((double)counts[ee] * (1.0 / (NTOK*2))) * (sm[ee] * (1.0 / NTOK));
    outaux[0] = (float)(0.08 * aux);   // AUX_COEF * E
  }
}

// ---------------- MoE w1/w3 fused dual-GEMM + SiLU*gate epilogue -> h (bf16) ----------------
__global__ __launch_bounds__(256) void moe13_kernel(
    const short* __restrict__ xn2,
    const float* __restrict__ ew1, const float* __restrict__ eb1,
    const float* __restrict__ ew3, const float* __restrict__ eb3,
    const int* __restrict__ counts, const int* __restrict__ off,
    const int* __restrict__ tok_of_slot, short* __restrict__ hbuf) {
  int e = blockIdx.z;
  int Me = counts[e];
  int m0 = blockIdx.y * 128;
  if (m0 >= Me) return;
  int base = off[e];
  int i0 = blockIdx.x * 64;
  __shared__ short As[128*40];
  __shared__ short W1s[64*40];
  __shared__ short W3s[64*40];
  int tid = threadIdx.x, lane = tid & 63, wid = tid >> 6;
  int wm = wid >> 1, wn = wid & 1;
  floatx4 zero4 = {0.f,0.f,0.f,0.f};
  floatx4 acc1[4][2], acc3[4][2];
  #pragma unroll
  for (int mi = 0; mi < 4; mi++)
    #pragma unroll
    for (int nj = 0; nj < 2; nj++) { acc1[mi][nj] = zero4; acc3[mi][nj] = zero4; }

  int ar = tid >> 1, ak = (tid & 1) * 8;
  int am = m0 + ar;
  bool aval = (am < Me);
  const short* Ag = xn2 + (size_t)(aval ? tok_of_slot[base + am] : 0) * DMODEL;
  int wr = tid >> 2, wk = (tid & 3) * 8;
  const float* W1g = ew1 + ((size_t)e*IDIM + i0 + wr)*DMODEL + wk;
  const float* W3g = ew3 + ((size_t)e*IDIM + i0 + wr)*DMODEL + wk;
  int rsel = lane & 15, kseg = (lane >> 4) * 8;

  for (int kk = 0; kk < DMODEL; kk += 32) {
    bf16x8 a0 = {0,0,0,0,0,0,0,0}, a1 = {0,0,0,0,0,0,0,0};
    if (aval) {
      a0 = *(const bf16x8*)(Ag + kk + ak);
      a1 = *(const bf16x8*)(Ag + kk + ak + 16);
    }
    floatx4 u0 = *(const floatx4*)(W1g + kk);
    floatx4 u1 = *(const floatx4*)(W1g + kk + 4);
    floatx4 v0 = *(const floatx4*)(W3g + kk);
    floatx4 v1 = *(const floatx4*)(W3g + kk + 4);
    __syncthreads();
    *(bf16x8*)(&As[ar*40 + ak])      = a0;
    *(bf16x8*)(&As[ar*40 + ak + 16]) = a1;
    bf16x8 wb1, wb3;
    wb1[0]=f2bf(u0[0]); wb1[1]=f2bf(u0[1]); wb1[2]=f2bf(u0[2]); wb1[3]=f2bf(u0[3]);
    wb1[4]=f2bf(u1[0]); wb1[5]=f2bf(u1[1]); wb1[6]=f2bf(u1[2]); wb1[7]=f2bf(u1[3]);
    wb3[0]=f2bf(v0[0]); wb3[1]=f2bf(v0[1]); wb3[2]=f2bf(v0[2]); wb3[3]=f2bf(v0[3]);
    wb3[4]=f2bf(v1[0]); wb3[5]=f2bf(v1[1]); wb3[6]=f2bf(v1[2]); wb3[7]=f2bf(v1[3]);
    *(bf16x8*)(&W1s[wr*40 + wk]) = wb1;
    *(bf16x8*)(&W3s[wr*40 + wk]) = wb3;
    __syncthreads();
    bf16x8 af[4], w1f[2], w3f[2];
    #pragma unroll
    for (int mi = 0; mi < 4; mi++)
      af[mi] = *(const bf16x8*)(&As[(wm*64 + mi*16 + rsel)*40 + kseg]);
    #pragma unroll
    for (int nj = 0; nj < 2; nj++) {
      w1f[nj] = *(const bf16x8*)(&W1s[(wn*32 + nj*16 + rsel)*40 + kseg]);
      w3f[nj] = *(const bf16x8*)(&W3s[(wn*32 + nj*16 + rsel)*40 + kseg]);
    }
    #pragma unroll
    for (int mi = 0; mi < 4; mi++)
      #pragma unroll
      for (int nj = 0; nj < 2; nj++) {
        acc1[mi][nj] = __builtin_amdgcn_mfma_f32_16x16x32_bf16(af[mi], w1f[nj], acc1[mi][nj], 0, 0, 0);
        acc3[mi][nj] = __builtin_amdgcn_mfma_f32_16x16x32_bf16(af[mi], w3f[nj], acc3[mi][nj], 0, 0, 0);
      }
  }
  int rj = (lane >> 4) * 4, cn = lane & 15;
  #pragma unroll
  for (int mi = 0; mi < 4; mi++) {
    #pragma unroll
    for (int nj = 0; nj < 2; nj++) {
      int i = i0 + wn*32 + nj*16 + cn;
      float be1 = eb1[e*IDIM + i], be3 = eb3[e*IDIM + i];
      #pragma unroll
      for (int j = 0; j < 4; j++) {
        int m = m0 + wm*64 + mi*16 + rj + j;
        if (m < Me) {
          float a = acc1[mi][nj][j] + be1;
          float b = acc3[mi][nj][j] + be3;
          float hval = (a / (1.f + __expf(-a))) * b;
          hbuf[(size_t)(base + m)*IDIM + i] = f2bf(hval);
        }
      }
    }
  }
}

// ---------------- MoE w2 GEMM, gate-scaled epilogue -> yslot (fp32) ----------------
__global__ __launch_bounds__(256) void moe2_kernel(
    const short* __restrict__ hbuf, const float* __restrict__ ew2, const float* __restrict__ eb2,
    const int* __restrict__ counts, const int* __restrict__ off,
    const float* __restrict__ gate_of_slot, float* __restrict__ yslot) {
  int e = blockIdx.z;
  int Me = counts[e];
  int m0 = blockIdx.y * 128;
  if (m0 >= Me) return;
  int base = off[e];
  int n0 = blockIdx.x * 128;
  __shared__ short As[128*40];
  __shared__ short Ws[128*40];
  int tid = threadIdx.x, lane = tid & 63, wid = tid >> 6;
  int wm = wid >> 1, wn = wid & 1;
  floatx4 zero4 = {0.f,0.f,0.f,0.f};
  floatx4 acc[4][4];
  #pragma unroll
  for (int mi = 0; mi < 4; mi++)
    #pragma unroll
    for (int nj = 0; nj < 4; nj++) acc[mi][nj] = zero4;

  int ar = tid >> 1, ak = (tid & 1) * 8, kw = (tid & 1) * 16;
  bool aval = (m0 + ar) < Me;
  const short* Ag = hbuf + (size_t)(base + (aval ? (m0 + ar) : 0)) * IDIM;
  const float* Wg = ew2 + ((size_t)e*DMODEL + n0 + ar)*IDIM;
  int rsel = lane & 15, kseg = (lane >> 4) * 8;

  for (int kk = 0; kk < IDIM; kk += 32) {
    bf16x8 a0 = {0,0,0,0,0,0,0,0}, a1 = {0,0,0,0,0,0,0,0};
    if (aval) {
      a0 = *(const bf16x8*)(Ag + kk + ak);
      a1 = *(const bf16x8*)(Ag + kk + ak + 16);
    }
    floatx4 w0 = *(const floatx4*)(Wg + kk + kw);
    floatx4 w1 = *(const floatx4*)(Wg + kk + kw + 4);
    floatx4 w2 = *(const floatx4*)(Wg + kk + kw + 8);
    floatx4 w3 = *(const floatx4*)(Wg + kk + kw + 12);
    __syncthreads();
    *(bf16x8*)(&As[ar*40 + ak])      = a0;
    *(bf16x8*)(&As[ar*40 + ak + 16]) = a1;
    bf16x8 wb0, wb1;
    wb0[0]=f2bf(w0[0]); wb0[1]=f2bf(w0[1]); wb0[2]=f2bf(w0[2]); wb0[3]=f2bf(w0[3]);
    wb0[4]=f2bf(w1[0]); wb0[5]=f2bf(w1[1]); wb0[6]=f2bf(w1[2]); wb0[7]=f2bf(w1[3]);
    wb1[0]=f2bf(w2[0]); wb1[1]=f2bf(w2[1]); wb1[2]=f2bf(w2[2]); wb1[3]=f2bf(w2[3]);
    wb1[4]=f2bf(w3[0]); wb1[5]=f2bf(w3[1]); wb1[6]=f2bf(w3[2]); wb1[7]=f2bf(w3[3]);
    *(bf16x8*)(&Ws[ar*40 + kw])     = wb0;
    *(bf16x8*)(&Ws[ar*40 + kw + 8]) = wb1;
    __syncthreads();
    bf16x8 af[4], wf[4];
    #pragma unroll
    for (int mi = 0; mi < 4; mi++)
      af[mi] = *(const bf16x8*)(&As[(wm*64 + mi*16 + rsel)*40 + kseg]);
    #pragma unroll
    for (int nj = 0; nj < 4; nj++)
      wf[nj] = *(const bf16x8*)(&Ws[(wn*64 + nj*16 + rsel)*40 + kseg]);
    #pragma unroll
    for (int mi = 0; mi < 4; mi++)
      #pragma unroll
      for (int nj = 0; nj < 4; nj++)
        acc[mi][nj] = __builtin_amdgcn_mfma_f32_16x16x32_bf16(af[mi], wf[nj], acc[mi][nj], 0, 0, 0);
  }
  int rj = (lane >> 4) * 4, cn = lane & 15;
  #pragma unroll
  for (int mi = 0; mi < 4; mi++) {
    #pragma unroll
    for (int nj = 0; nj < 4; nj++) {
      int n = n0 + wn*64 + nj*16 + cn;
      float bn = eb2[e*DMODEL + n];
      #pragma unroll
      for (int j = 0; j < 4; j++) {
        int m = m0 + wm*64 + mi*16 + rj + j;
        if (m < Me) {
          float g = gate_of_slot[base + m];
          yslot[(size_t)(base + m)*DMODEL + n] = (acc[mi][nj][j] + bn) * g;
        }
      }
    }
  }
}

// ---------------- combine: out = h1 + yslot[sA] + yslot[sB] ----------------
__global__ __launch_bounds__(256) void combine_kernel(
    const float* __restrict__ h1, const float* __restrict__ yslot,
    const int* __restrict__ slot_of_tok, float* __restrict__ out) {
  int n = blockIdx.x, t = threadIdx.x;
  int sA = slot_of_tok[2*n], sB = slot_of_tok[2*n+1];
  const floatx4* a  = (const floatx4*)(h1 + (size_t)n*DMODEL);
  const floatx4* ya = (const floatx4*)(yslot + (size_t)sA*DMODEL);
  const floatx4* yb = (const floatx4*)(yslot + (size_t)sB*DMODEL);
  floatx4 v = a[t] + ya[t] + yb[t];
  ((floatx4*)(out + (size_t)n*DMODEL))[t] = v;
}

extern "C" void kernel_launch(void* const* d_in, const int* in_sizes, int n_in,
                              void* d_out, int out_size, void* d_ws, size_t ws_size,
                              hipStream_t stream) {
  const float* x      = (const float*)d_in[0];
  const float* qkv_w  = (const float*)d_in[1];
  const float* qkv_b  = (const float*)d_in[2];
  const float* out_w  = (const float*)d_in[3];
  const float* out_b  = (const float*)d_in[4];
  const float* ln1_w  = (const float*)d_in[5];
  const float* ln2_w  = (const float*)d_in[6];
  const float* gate_w = (const float*)d_in[7];
  const float* ew1    = (const float*)d_in[8];
  const float* eb1    = (const float*)d_in[9];
  const float* ew2    = (const float*)d_in[10];
  const float* eb2    = (const float*)d_in[11];
  const float* ew3    = (const float*)d_in[12];
  const float* eb3    = (const float*)d_in[13];
  float* out = (float*)d_out;

  // ---- workspace layout (max 84.3 MB; 96.1 MB proven safe in rounds 1-3) ----
  // Step order:  (1)rope_table (2)rmsnorm1 (3)qkv-gemm (4)rope (5)attn
  //              (6)outproj-gemm (7)rmsnorm2 (8)gate (9)offsets/scatter/aux
  //              (10)moe13 (11)moe2 (12)combine
  char* ws = (char*)d_ws;
  float* xn1f   = (float*)(ws + 0);          // 8 MB, live 2..3
  float* attnof = (float*)(ws + 0);          // 8 MB, live 5..6 (xn1f dead)
  float* qkvf   = (float*)(ws + 8388608);    // 24 MB, live 3..4
  float* h1     = (float*)(ws + 8388608);    // 8 MB, live 6..12 (qkvf dead after 4)
  short* xn2    = (short*)(ws + 16777216);   // 4 MB, live 7..10 (inside dead qkvf)
  float* qrf    = (float*)(ws + 33554432);   // 8 MB, live 4..5
  float* krf    = (float*)(ws + 41943040);   // 8 MB, live 4..5
  float* vrf    = (float*)(ws + 50331648);   // 8 MB, live 4..5
  short* hbuf   = (short*)(ws + 33554432);   // 32 MB, live 10..11 (q/k/v dead after 5)
  float* yslot  = (float*)(ws + 67108864);   // 16 MB, live 11..12; ends at 80 MB
  // small buffers, disjoint from everything above (80 MB+):
  float* cost         = (float*)(ws + 83886080);  // 128 KB, live 1..4
  float* sint         = (float*)(ws + 84017152);  // 128 KB, live 1..4
  float* probs        = (float*)(ws + 84148224);  //  64 KB, live 8..9
  int*   ctrl         = (int*)  (ws + 84213760);  //   1 KB, live 8..11
  int*   pair         = (int*)  (ws + 84214784);  //  16 KB, live 8..9
  float* gpair        = (float*)(ws + 84231168);  //  16 KB, live 8..9
  int*   slot_of_tok  = (int*)  (ws + 84247552);  //  16 KB, live 9..12
  int*   tok_of_slot  = (int*)  (ws + 84263936);  //  16 KB, live 9..10
  float* gate_of_slot = (float*)(ws + 84280320);  //  16 KB, live 9..11

  int* counts = ctrl;
  int* off    = ctrl + 8;
  int* cursor = ctrl + 20;

  hipMemsetAsync(ctrl, 0, 1024, stream);
  rope_table_kernel<<<T_SEQ, 32, 0, stream>>>(cost, sint);
  rmsnorm_f32_kernel<<<NTOK, 256, 0, stream>>>(x, ln1_w, xn1f);
  gemm_f32<0><<<dim3(48, 16), 256, 0, stream>>>(xn1f, qkv_w, qkv_b, nullptr, qkvf, 3072, DMODEL);
  rope_kernel<<<8192, 256, 0, stream>>>(qkvf, cost, sint, qrf, krf, vrf);
  attn_kernel<<<8192, 256, 0, stream>>>(qrf, krf, vrf, attnof);
  gemm_f32<1><<<dim3(16, 16), 256, 0, stream>>>(attnof, out_w, out_b, x, h1, DMODEL, DMODEL);
  rmsnorm_bf16_kernel<<<NTOK, 256, 0, stream>>>(h1, ln2_w, xn2);
  gate_kernel<<<NTOK, 64, 0, stream>>>(h1, ln2_w, gate_w, probs, pair, gpair, counts);
  offsets_kernel<<<1, 64, 0, stream>>>(counts, off, cursor);
  scatter_kernel<<<8, 256, 0, stream>>>(pair, gpair, cursor, tok_of_slot, gate_of_slot, slot_of_tok);
  aux_kernel<<<1, 256, 0, stream>>>(probs, counts, out + 2097152);
  moe13_kernel<<<dim3(64, 16, 8), 256, 0, stream>>>(xn2, ew1, eb1, ew3, eb3, counts, off, tok_of_slot, hbuf);
  moe2_kernel<<<dim3(8, 16, 8), 256, 0, stream>>>(hbuf, ew2, eb2, counts, off, gate_of_slot, yslot);
  combine_kernel<<<NTOK, 256, 0, stream>>>(h1, yslot, slot_of_tok, out);
}

// Round 6
// 965.917 us; speedup vs baseline: 1.8549x; 1.8549x over previous
//
#include <hip/hip_runtime.h>
#include <cstdint>
#include <cstddef>
#include <math.h>

#define T_SEQ  1024
#define DMODEL 1024
#define NHEAD  16
#define HDIM   64
#define NEXP   8
#define IDIM   4096
#define NTOK   2048
#define NSLOT  4096

typedef short bf16x8 __attribute__((ext_vector_type(8)));
typedef short s16x4  __attribute__((ext_vector_type(4)));
typedef float floatx4 __attribute__((ext_vector_type(4)));

__device__ __forceinline__ float bf2f(short s) {
  return __uint_as_float(((unsigned)(unsigned short)s) << 16);
}
__device__ __forceinline__ short f2bf(float f) {
  unsigned u = __float_as_uint(f);
  unsigned r = (u + 0x7FFFu + ((u >> 16) & 1u)) >> 16;
  return (short)r;
}

// ---------------- RMSNorm: fp32 in -> fp32 out ----------------
__global__ __launch_bounds__(256) void rmsnorm_f32_kernel(
    const float* __restrict__ x, const float* __restrict__ w, float* __restrict__ out) {
  int row = blockIdx.x, tid = threadIdx.x;
  const floatx4* xr = (const floatx4*)(x + (size_t)row * DMODEL);
  floatx4 v = xr[tid];
  float ss = v[0]*v[0] + v[1]*v[1] + v[2]*v[2] + v[3]*v[3];
  #pragma unroll
  for (int off = 32; off > 0; off >>= 1) ss += __shfl_xor(ss, off);
  __shared__ float wsum[4];
  int wid = tid >> 6;
  if ((tid & 63) == 0) wsum[wid] = ss;
  __syncthreads();
  float tot = wsum[0] + wsum[1] + wsum[2] + wsum[3];
  float r = rsqrtf(tot * (1.0f / DMODEL) + 1e-6f);
  floatx4 wv = ((const floatx4*)w)[tid];
  floatx4 o;
  o[0] = v[0]*r*wv[0]; o[1] = v[1]*r*wv[1];
  o[2] = v[2]*r*wv[2]; o[3] = v[3]*r*wv[3];
  ((floatx4*)(out + (size_t)row * DMODEL))[tid] = o;
}

// ---------------- RMSNorm: fp32 in -> bf16 out (for MoE input) ----------------
__global__ __launch_bounds__(256) void rmsnorm_bf16_kernel(
    const float* __restrict__ x, const float* __restrict__ w, short* __restrict__ out) {
  int row = blockIdx.x, tid = threadIdx.x;
  const floatx4* xr = (const floatx4*)(x + (size_t)row * DMODEL);
  floatx4 v = xr[tid];
  float ss = v[0]*v[0] + v[1]*v[1] + v[2]*v[2] + v[3]*v[3];
  #pragma unroll
  for (int off = 32; off > 0; off >>= 1) ss += __shfl_xor(ss, off);
  __shared__ float wsum[4];
  int wid = tid >> 6;
  if ((tid & 63) == 0) wsum[wid] = ss;
  __syncthreads();
  float tot = wsum[0] + wsum[1] + wsum[2] + wsum[3];
  float r = rsqrtf(tot * (1.0f / DMODEL) + 1e-6f);
  floatx4 wv = ((const floatx4*)w)[tid];
  s16x4 o;
  o[0] = f2bf(v[0]*r*wv[0]); o[1] = f2bf(v[1]*r*wv[1]);
  o[2] = f2bf(v[2]*r*wv[2]); o[3] = f2bf(v[3]*r*wv[3]);
  *(s16x4*)(out + (size_t)row * DMODEL + tid*4) = o;
}

// ---------------- fp32 vector-ALU GEMM: C = A(MxK) @ W(NxK)^T + bias [+resid] ----------------
template<int RESID>
__global__ __launch_bounds__(256) void gemm_f32(
    const float* __restrict__ A, const float* __restrict__ W,
    const float* __restrict__ bias, const float* __restrict__ resid,
    float* __restrict__ C, int N, int K) {
  __shared__ float Ast[16][132];   // [k][m]
  __shared__ float Bst[16][68];    // [k][n]
  int tid = threadIdx.x;
  int m0 = blockIdx.y * 128, n0 = blockIdx.x * 64;
  int ar = tid >> 1, ac = (tid & 1) * 8;
  int br = tid >> 2, bc = (tid & 3) * 4;
  int ty = tid >> 4, tx = tid & 15;

  float acc[8][4];
  #pragma unroll
  for (int i = 0; i < 8; i++)
    #pragma unroll
    for (int j = 0; j < 4; j++) acc[i][j] = 0.f;

  const float* Ap = A + (size_t)(m0 + ar) * K;
  const float* Wp = W + (size_t)(n0 + br) * K;

  for (int kk = 0; kk < K; kk += 16) {
    floatx4 a0 = *(const floatx4*)(Ap + kk + ac);
    floatx4 a1 = *(const floatx4*)(Ap + kk + ac + 4);
    floatx4 b0 = *(const floatx4*)(Wp + kk + bc);
    __syncthreads();
    #pragma unroll
    for (int j = 0; j < 4; j++) {
      Ast[ac + j][ar]     = a0[j];
      Ast[ac + 4 + j][ar] = a1[j];
      Bst[bc + j][br]     = b0[j];
    }
    __syncthreads();
    #pragma unroll
    for (int k = 0; k < 16; k++) {
      floatx4 av0 = *(const floatx4*)(&Ast[k][ty*8]);
      floatx4 av1 = *(const floatx4*)(&Ast[k][ty*8 + 4]);
      floatx4 bv  = *(const floatx4*)(&Bst[k][tx*4]);
      #pragma unroll
      for (int i = 0; i < 4; i++)
        #pragma unroll
        for (int j = 0; j < 4; j++) {
          acc[i][j]   = fmaf(av0[i], bv[j], acc[i][j]);
          acc[4+i][j] = fmaf(av1[i], bv[j], acc[4+i][j]);
        }
    }
  }
  #pragma unroll
  for (int i = 0; i < 8; i++) {
    int m = m0 + ty*8 + i;
    #pragma unroll
    for (int j = 0; j < 4; j++) {
      int n = n0 + tx*4 + j;
      float v = acc[i][j] + bias[n];
      if (RESID) v += resid[(size_t)m * N + n];
      C[(size_t)m * N + n] = v;
    }
  }
}

// ---------------- RoPE table (fp64 generation) ----------------
__global__ void rope_table_kernel(float* __restrict__ cost, float* __restrict__ sint) {
  int t = blockIdx.x, d = threadIdx.x;  // block 32
  double theta = pow(10000.0, -(double)d / 32.0);
  double f = (double)t * theta;
  cost[t*32 + d] = (float)cos(f);
  sint[t*32 + d] = (float)sin(f);
}

// ---------------- RoPE + transpose to [B][H][T][hd], fp32 ----------------
__global__ __launch_bounds__(256) void rope_kernel(
    const float* __restrict__ qkv, const float* __restrict__ cost, const float* __restrict__ sint,
    float* __restrict__ qr, float* __restrict__ kr, float* __restrict__ vr) {
  int wid = threadIdx.x >> 6, lane = threadIdx.x & 63;
  int idx = blockIdx.x * 4 + wid;        // over NTOK*NHEAD
  int h = idx & 15, n = idx >> 4;
  int t = n & (T_SEQ - 1), b = n >> 10;
  const float* base = qkv + (size_t)n * 3072 + h * 192;
  int d2 = lane & 31;
  float c = cost[t*32 + d2], s = sint[t*32 + d2];
  float q1 = base[d2],      q2 = base[d2 + 32];
  float k1 = base[64 + d2], k2 = base[96 + d2];
  float qo = (lane < 32) ? (q1*c - q2*s) : (q1*s + q2*c);
  float ko = (lane < 32) ? (k1*c - k2*s) : (k1*s + k2*c);
  size_t orow = ((size_t)(b*NHEAD + h) * T_SEQ + t) * HDIM;
  qr[orow + lane] = qo;
  kr[orow + lane] = ko;
  vr[orow + lane] = base[128 + lane];
}

// ---------------- flash attention, fp32, LDS-tiled ----------------
// Block: 256 threads = 32 q-rows of one (b,h). K-tiles of 64.
// Thread (qg,kj): qg=tid>>4 owns q-rows {2qg,2qg+1}; kj=tid&15 owns cols {kj+16t}.
// All LDS rows padded to 65 floats -> every access pattern is conflict-free
// (16 consecutive banks, x4 broadcast).  State in registers: ~45 VGPR, no spill.
__global__ __launch_bounds__(256) void attn_flash_kernel(
    const float* __restrict__ qr_, const float* __restrict__ kr_,
    const float* __restrict__ vr_, float* __restrict__ attno) {
  __shared__ float Qs[32][65];
  __shared__ float Ks[64][65];
  __shared__ float Vs[64][65];
  __shared__ float Ps[32][65];
  int tid = threadIdx.x;
  int bh = blockIdx.y;
  int qt = (int)gridDim.x - 1 - (int)blockIdx.x;   // heavy tiles first
  int q0 = qt * 32;
  const float* Qb = qr_ + ((size_t)bh * T_SEQ + q0) * HDIM;
  const float* Kb = kr_ + (size_t)bh * T_SEQ * HDIM;
  const float* Vb = vr_ + (size_t)bh * T_SEQ * HDIM;

  // stage Q (32x64)
  {
    int r = tid >> 3, seg = (tid & 7) * 8;
    floatx4 a = *(const floatx4*)(Qb + r*HDIM + seg);
    floatx4 b = *(const floatx4*)(Qb + r*HDIM + seg + 4);
    #pragma unroll
    for (int j = 0; j < 4; j++) { Qs[r][seg+j] = a[j]; Qs[r][seg+4+j] = b[j]; }
  }

  int qg = tid >> 4, kj = tid & 15;
  int qr0 = qg*2, qr1 = qr0 + 1;
  int q_g0 = q0 + qr0, q_g1 = q_g0 + 1;
  float m0 = -1e30f, m1 = -1e30f, l0 = 0.f, l1 = 0.f;
  float O0[4] = {0,0,0,0}, O1[4] = {0,0,0,0};
  const float scale = 0.03125f;   // (D=1024)^-0.5 per reference

  int ntiles = (q0 + 32 + 63) >> 6;
  int sr = tid >> 2, sseg = (tid & 3) * 16;
  const float* Kg = Kb + (size_t)sr * HDIM + sseg;
  const float* Vg = Vb + (size_t)sr * HDIM + sseg;

  for (int kt = 0; kt < ntiles; kt++) {
    int kbase = kt << 6;
    // ---- stage K,V tile (64x64 each), coalesced float4 ----
    const float* kp = Kg + (size_t)kbase * HDIM;
    const float* vp = Vg + (size_t)kbase * HDIM;
    floatx4 ka = *(const floatx4*)(kp);
    floatx4 kb = *(const floatx4*)(kp + 4);
    floatx4 kc = *(const floatx4*)(kp + 8);
    floatx4 kd = *(const floatx4*)(kp + 12);
    floatx4 va = *(const floatx4*)(vp);
    floatx4 vb = *(const floatx4*)(vp + 4);
    floatx4 vc = *(const floatx4*)(vp + 8);
    floatx4 vd = *(const floatx4*)(vp + 12);
    __syncthreads();   // previous tile's reads complete before overwrite
    #pragma unroll
    for (int j = 0; j < 4; j++) {
      Ks[sr][sseg+j]    = ka[j]; Ks[sr][sseg+4+j]  = kb[j];
      Ks[sr][sseg+8+j]  = kc[j]; Ks[sr][sseg+12+j] = kd[j];
      Vs[sr][sseg+j]    = va[j]; Vs[sr][sseg+4+j]  = vb[j];
      Vs[sr][sseg+8+j]  = vc[j]; Vs[sr][sseg+12+j] = vd[j];
    }
    __syncthreads();
    // ---- scores: s[2 rows][4 cols] ----
    float s0[4] = {0,0,0,0}, s1[4] = {0,0,0,0};
    #pragma unroll 8
    for (int d = 0; d < 64; d++) {
      float qa = Qs[qr0][d], qb = Qs[qr1][d];
      #pragma unroll
      for (int t = 0; t < 4; t++) {
        float kv = Ks[kj + 16*t][d];
        s0[t] = fmaf(qa, kv, s0[t]);
        s1[t] = fmaf(qb, kv, s1[t]);
      }
    }
    // ---- causal mask + scale + row max ----
    float pm0 = -1e30f, pm1 = -1e30f;
    #pragma unroll
    for (int t = 0; t < 4; t++) {
      int kc_ = kbase + kj + 16*t;
      s0[t] = (kc_ <= q_g0) ? s0[t]*scale : -1e30f;
      s1[t] = (kc_ <= q_g1) ? s1[t]*scale : -1e30f;
      pm0 = fmaxf(pm0, s0[t]); pm1 = fmaxf(pm1, s1[t]);
    }
    #pragma unroll
    for (int off = 1; off < 16; off <<= 1) {
      pm0 = fmaxf(pm0, __shfl_xor(pm0, off));
      pm1 = fmaxf(pm1, __shfl_xor(pm1, off));
    }
    // ---- online softmax update ----
    float mn0 = fmaxf(m0, pm0), mn1 = fmaxf(m1, pm1);
    float sc0 = __expf(m0 - mn0), sc1 = __expf(m1 - mn1);
    float rs0 = 0.f, rs1 = 0.f;
    #pragma unroll
    for (int t = 0; t < 4; t++) {
      float p0 = (s0[t] > -1e29f) ? __expf(s0[t] - mn0) : 0.f;
      float p1 = (s1[t] > -1e29f) ? __expf(s1[t] - mn1) : 0.f;
      rs0 += p0; rs1 += p1;
      Ps[qr0][kj + 16*t] = p0;
      Ps[qr1][kj + 16*t] = p1;
    }
    #pragma unroll
    for (int off = 1; off < 16; off <<= 1) {
      rs0 += __shfl_xor(rs0, off);
      rs1 += __shfl_xor(rs1, off);
    }
    l0 = l0*sc0 + rs0; l1 = l1*sc1 + rs1;
    m0 = mn0; m1 = mn1;
    #pragma unroll
    for (int t = 0; t < 4; t++) { O0[t] *= sc0; O1[t] *= sc1; }
    __syncthreads();   // P visible to all
    // ---- PV: O[row][kj+16t] += P[row][k] * V[k][kj+16t] ----
    #pragma unroll 8
    for (int k = 0; k < 64; k++) {
      float pa = Ps[qr0][k], pb = Ps[qr1][k];
      #pragma unroll
      for (int t = 0; t < 4; t++) {
        float vv = Vs[k][kj + 16*t];
        O0[t] = fmaf(pa, vv, O0[t]);
        O1[t] = fmaf(pb, vv, O1[t]);
      }
    }
  }
  // ---- epilogue ----
  int b = bh >> 4, h = bh & 15;
  float inv0 = 1.0f / l0, inv1 = 1.0f / l1;
  float* o0 = attno + ((size_t)(b*T_SEQ + q_g0))*DMODEL + h*HDIM;
  float* o1 = o0 + DMODEL;
  #pragma unroll
  for (int t = 0; t < 4; t++) {
    o0[kj + 16*t] = O0[t]*inv0;
    o1[kj + 16*t] = O1[t]*inv1;
  }
}

// ---------------- gate: FULL FP64 path (inline rmsnorm of fp32-accurate h1) ----------------
__global__ __launch_bounds__(64) void gate_kernel(
    const float* __restrict__ h1, const float* __restrict__ lnw, const float* __restrict__ gw,
    float* __restrict__ probs, int* __restrict__ pair, float* __restrict__ gpair,
    int* __restrict__ counts) {
  int n = blockIdx.x, lane = threadIdx.x;
  const float* xp = h1 + (size_t)n * DMODEL + lane*16;
  float xv[16];
  double ss = 0.0;
  #pragma unroll
  for (int j = 0; j < 16; j++) { xv[j] = xp[j]; ss += (double)xv[j] * (double)xv[j]; }
  #pragma unroll
  for (int off = 32; off > 0; off >>= 1) ss += __shfl_xor(ss, off);
  double r = 1.0 / sqrt(ss * (1.0 / DMODEL) + 1e-6);
  const float* wp = lnw + lane*16;
  double xf[16];
  #pragma unroll
  for (int j = 0; j < 16; j++) xf[j] = (double)xv[j] * r * (double)wp[j];
  double logit[8];
  #pragma unroll
  for (int e = 0; e < 8; e++) {
    const float* g = gw + e*DMODEL + lane*16;
    double acc = 0.0;
    #pragma unroll
    for (int j = 0; j < 16; j++) acc += xf[j] * (double)g[j];
    logit[e] = acc;
  }
  #pragma unroll
  for (int e = 0; e < 8; e++)
    #pragma unroll
    for (int off = 32; off > 0; off >>= 1) logit[e] += __shfl_xor(logit[e], off);
  double mxl = logit[0];
  #pragma unroll
  for (int e = 1; e < 8; e++) mxl = fmax(mxl, logit[e]);
  double p[8], Z = 0.0;
  #pragma unroll
  for (int e = 0; e < 8; e++) { p[e] = exp(logit[e] - mxl); Z += p[e]; }
  double invZ = 1.0 / Z;
  #pragma unroll
  for (int e = 0; e < 8; e++) p[e] *= invZ;
  int e0 = 0; double b0 = p[0];
  #pragma unroll
  for (int e = 1; e < 8; e++) if (p[e] > b0) { b0 = p[e]; e0 = e; }
  int e1 = -1; double b1 = -1.0;
  #pragma unroll
  for (int e = 0; e < 8; e++) if (e != e0 && p[e] > b1) { b1 = p[e]; e1 = e; }
  if (lane == 0) {
    #pragma unroll
    for (int e = 0; e < 8; e++) probs[n*8 + e] = (float)p[e];
    pair[2*n] = e0; pair[2*n+1] = e1;
    gpair[2*n] = (float)b0; gpair[2*n+1] = (float)b1;
    atomicAdd(&counts[e0], 1);
    atomicAdd(&counts[e1], 1);
  }
}

__global__ void offsets_kernel(const int* __restrict__ counts, int* __restrict__ off,
                               int* __restrict__ cursor) {
  if (threadIdx.x == 0) {
    int a = 0;
    for (int e = 0; e < 8; e++) { off[e] = a; cursor[e] = a; a += counts[e]; }
    off[8] = a;
  }
}

__global__ __launch_bounds__(256) void scatter_kernel(
    const int* __restrict__ pair, const float* __restrict__ gpair, int* __restrict__ cursor,
    int* __restrict__ tok_of_slot, float* __restrict__ gate_of_slot, int* __restrict__ slot_of_tok) {
  int n = blockIdx.x * 256 + threadIdx.x;
  int e0 = pair[2*n], e1 = pair[2*n+1];
  int s0 = atomicAdd(&cursor[e0], 1);
  tok_of_slot[s0] = n; gate_of_slot[s0] = gpair[2*n];   slot_of_tok[2*n] = s0;
  int s1 = atomicAdd(&cursor[e1], 1);
  tok_of_slot[s1] = n; gate_of_slot[s1] = gpair[2*n+1]; slot_of_tok[2*n+1] = s1;
}

__global__ __launch_bounds__(256) void aux_kernel(
    const float* __restrict__ probs, const int* __restrict__ counts, float* __restrict__ outaux) {
  __shared__ double sm[256];
  int t = threadIdx.x;
  int e = t & 7, base = t >> 3;
  double acc = 0.0;
  for (int n = base; n < NTOK; n += 32) acc += (double)probs[n*8 + e];
  sm[t] = acc;
  __syncthreads();
  if (t < 8) {
    double s = 0.0;
    for (int g = 0; g < 32; g++) s += sm[g*8 + t];
    sm[t] = s;
  }
  __syncthreads();
  if (t == 0) {
    double aux = 0.0;
    for (int ee = 0; ee < 8; ee++)
      aux += ((double)counts[ee] * (1.0 / (NTOK*2))) * (sm[ee] * (1.0 / NTOK));
    outaux[0] = (float)(0.08 * aux);   // AUX_COEF * E
  }
}

// ---------------- MoE w1/w3 fused dual-GEMM + SiLU*gate epilogue -> h (bf16) ----------------
__global__ __launch_bounds__(256) void moe13_kernel(
    const short* __restrict__ xn2,
    const float* __restrict__ ew1, const float* __restrict__ eb1,
    const float* __restrict__ ew3, const float* __restrict__ eb3,
    const int* __restrict__ counts, const int* __restrict__ off,
    const int* __restrict__ tok_of_slot, short* __restrict__ hbuf) {
  int e = blockIdx.z;
  int Me = counts[e];
  int m0 = blockIdx.y * 128;
  if (m0 >= Me) return;
  int base = off[e];
  int i0 = blockIdx.x * 64;
  __shared__ short As[128*40];
  __shared__ short W1s[64*40];
  __shared__ short W3s[64*40];
  int tid = threadIdx.x, lane = tid & 63, wid = tid >> 6;
  int wm = wid >> 1, wn = wid & 1;
  floatx4 zero4 = {0.f,0.f,0.f,0.f};
  floatx4 acc1[4][2], acc3[4][2];
  #pragma unroll
  for (int mi = 0; mi < 4; mi++)
    #pragma unroll
    for (int nj = 0; nj < 2; nj++) { acc1[mi][nj] = zero4; acc3[mi][nj] = zero4; }

  int ar = tid >> 1, ak = (tid & 1) * 8;
  int am = m0 + ar;
  bool aval = (am < Me);
  const short* Ag = xn2 + (size_t)(aval ? tok_of_slot[base + am] : 0) * DMODEL;
  int wr = tid >> 2, wk = (tid & 3) * 8;
  const float* W1g = ew1 + ((size_t)e*IDIM + i0 + wr)*DMODEL + wk;
  const float* W3g = ew3 + ((size_t)e*IDIM + i0 + wr)*DMODEL + wk;
  int rsel = lane & 15, kseg = (lane >> 4) * 8;

  for (int kk = 0; kk < DMODEL; kk += 32) {
    bf16x8 a0 = {0,0,0,0,0,0,0,0}, a1 = {0,0,0,0,0,0,0,0};
    if (aval) {
      a0 = *(const bf16x8*)(Ag + kk + ak);
      a1 = *(const bf16x8*)(Ag + kk + ak + 16);
    }
    floatx4 u0 = *(const floatx4*)(W1g + kk);
    floatx4 u1 = *(const floatx4*)(W1g + kk + 4);
    floatx4 v0 = *(const floatx4*)(W3g + kk);
    floatx4 v1 = *(const floatx4*)(W3g + kk + 4);
    __syncthreads();
    *(bf16x8*)(&As[ar*40 + ak])      = a0;
    *(bf16x8*)(&As[ar*40 + ak + 16]) = a1;
    bf16x8 wb1, wb3;
    wb1[0]=f2bf(u0[0]); wb1[1]=f2bf(u0[1]); wb1[2]=f2bf(u0[2]); wb1[3]=f2bf(u0[3]);
    wb1[4]=f2bf(u1[0]); wb1[5]=f2bf(u1[1]); wb1[6]=f2bf(u1[2]); wb1[7]=f2bf(u1[3]);
    wb3[0]=f2bf(v0[0]); wb3[1]=f2bf(v0[1]); wb3[2]=f2bf(v0[2]); wb3[3]=f2bf(v0[3]);
    wb3[4]=f2bf(v1[0]); wb3[5]=f2bf(v1[1]); wb3[6]=f2bf(v1[2]); wb3[7]=f2bf(v1[3]);
    *(bf16x8*)(&W1s[wr*40 + wk]) = wb1;
    *(bf16x8*)(&W3s[wr*40 + wk]) = wb3;
    __syncthreads();
    bf16x8 af[4], w1f[2], w3f[2];
    #pragma unroll
    for (int mi = 0; mi < 4; mi++)
      af[mi] = *(const bf16x8*)(&As[(wm*64 + mi*16 + rsel)*40 + kseg]);
    #pragma unroll
    for (int nj = 0; nj < 2; nj++) {
      w1f[nj] = *(const bf16x8*)(&W1s[(wn*32 + nj*16 + rsel)*40 + kseg]);
      w3f[nj] = *(const bf16x8*)(&W3s[(wn*32 + nj*16 + rsel)*40 + kseg]);
    }
    #pragma unroll
    for (int mi = 0; mi < 4; mi++)
      #pragma unroll
      for (int nj = 0; nj < 2; nj++) {
        acc1[mi][nj] = __builtin_amdgcn_mfma_f32_16x16x32_bf16(af[mi], w1f[nj], acc1[mi][nj], 0, 0, 0);
        acc3[mi][nj] = __builtin_amdgcn_mfma_f32_16x16x32_bf16(af[mi], w3f[nj], acc3[mi][nj], 0, 0, 0);
      }
  }
  int rj = (lane >> 4) * 4, cn = lane & 15;
  #pragma unroll
  for (int mi = 0; mi < 4; mi++) {
    #pragma unroll
    for (int nj = 0; nj < 2; nj++) {
      int i = i0 + wn*32 + nj*16 + cn;
      float be1 = eb1[e*IDIM + i], be3 = eb3[e*IDIM + i];
      #pragma unroll
      for (int j = 0; j < 4; j++) {
        int m = m0 + wm*64 + mi*16 + rj + j;
        if (m < Me) {
          float a = acc1[mi][nj][j] + be1;
          float b = acc3[mi][nj][j] + be3;
          float hval = (a / (1.f + __expf(-a))) * b;
          hbuf[(size_t)(base + m)*IDIM + i] = f2bf(hval);
        }
      }
    }
  }
}

// ---------------- MoE w2 GEMM, gate-scaled epilogue -> yslot (fp32) ----------------
__global__ __launch_bounds__(256) void moe2_kernel(
    const short* __restrict__ hbuf, const float* __restrict__ ew2, const float* __restrict__ eb2,
    const int* __restrict__ counts, const int* __restrict__ off,
    const float* __restrict__ gate_of_slot, float* __restrict__ yslot) {
  int e = blockIdx.z;
  int Me = counts[e];
  int m0 = blockIdx.y * 128;
  if (m0 >= Me) return;
  int base = off[e];
  int n0 = blockIdx.x * 128;
  __shared__ short As[128*40];
  __shared__ short Ws[128*40];
  int tid = threadIdx.x, lane = tid & 63, wid = tid >> 6;
  int wm = wid >> 1, wn = wid & 1;
  floatx4 zero4 = {0.f,0.f,0.f,0.f};
  floatx4 acc[4][4];
  #pragma unroll
  for (int mi = 0; mi < 4; mi++)
    #pragma unroll
    for (int nj = 0; nj < 4; nj++) acc[mi][nj] = zero4;

  int ar = tid >> 1, ak = (tid & 1) * 8, kw = (tid & 1) * 16;
  bool aval = (m0 + ar) < Me;
  const short* Ag = hbuf + (size_t)(base + (aval ? (m0 + ar) : 0)) * IDIM;
  const float* Wg = ew2 + ((size_t)e*DMODEL + n0 + ar)*IDIM;
  int rsel = lane & 15, kseg = (lane >> 4) * 8;

  for (int kk = 0; kk < IDIM; kk += 32) {
    bf16x8 a0 = {0,0,0,0,0,0,0,0}, a1 = {0,0,0,0,0,0,0,0};
    if (aval) {
      a0 = *(const bf16x8*)(Ag + kk + ak);
      a1 = *(const bf16x8*)(Ag + kk + ak + 16);
    }
    floatx4 w0 = *(const floatx4*)(Wg + kk + kw);
    floatx4 w1 = *(const floatx4*)(Wg + kk + kw + 4);
    floatx4 w2 = *(const floatx4*)(Wg + kk + kw + 8);
    floatx4 w3 = *(const floatx4*)(Wg + kk + kw + 12);
    __syncthreads();
    *(bf16x8*)(&As[ar*40 + ak])      = a0;
    *(bf16x8*)(&As[ar*40 + ak + 16]) = a1;
    bf16x8 wb0, wb1;
    wb0[0]=f2bf(w0[0]); wb0[1]=f2bf(w0[1]); wb0[2]=f2bf(w0[2]); wb0[3]=f2bf(w0[3]);
    wb0[4]=f2bf(w1[0]); wb0[5]=f2bf(w1[1]); wb0[6]=f2bf(w1[2]); wb0[7]=f2bf(w1[3]);
    wb1[0]=f2bf(w2[0]); wb1[1]=f2bf(w2[1]); wb1[2]=f2bf(w2[2]); wb1[3]=f2bf(w2[3]);
    wb1[4]=f2bf(w3[0]); wb1[5]=f2bf(w3[1]); wb1[6]=f2bf(w3[2]); wb1[7]=f2bf(w3[3]);
    *(bf16x8*)(&Ws[ar*40 + kw])     = wb0;
    *(bf16x8*)(&Ws[ar*40 + kw + 8]) = wb1;
    __syncthreads();
    bf16x8 af[4], wf[4];
    #pragma unroll
    for (int mi = 0; mi < 4; mi++)
      af[mi] = *(const bf16x8*)(&As[(wm*64 + mi*16 + rsel)*40 + kseg]);
    #pragma unroll
    for (int nj = 0; nj < 4; nj++)
      wf[nj] = *(const bf16x8*)(&Ws[(wn*64 + nj*16 + rsel)*40 + kseg]);
    #pragma unroll
    for (int mi = 0; mi < 4; mi++)
      #pragma unroll
      for (int nj = 0; nj < 4; nj++)
        acc[mi][nj] = __builtin_amdgcn_mfma_f32_16x16x32_bf16(af[mi], wf[nj], acc[mi][nj], 0, 0, 0);
  }
  int rj = (lane >> 4) * 4, cn = lane & 15;
  #pragma unroll
  for (int mi = 0; mi < 4; mi++) {
    #pragma unroll
    for (int nj = 0; nj < 4; nj++) {
      int n = n0 + wn*64 + nj*16 + cn;
      float bn = eb2[e*DMODEL + n];
      #pragma unroll
      for (int j = 0; j < 4; j++) {
        int m = m0 + wm*64 + mi*16 + rj + j;
        if (m < Me) {
          float g = gate_of_slot[base + m];
          yslot[(size_t)(base + m)*DMODEL + n] = (acc[mi][nj][j] + bn) * g;
        }
      }
    }
  }
}

// ---------------- combine: out = h1 + yslot[sA] + yslot[sB] ----------------
__global__ __launch_bounds__(256) void combine_kernel(
    const float* __restrict__ h1, const float* __restrict__ yslot,
    const int* __restrict__ slot_of_tok, float* __restrict__ out) {
  int n = blockIdx.x, t = threadIdx.x;
  int sA = slot_of_tok[2*n], sB = slot_of_tok[2*n+1];
  const floatx4* a  = (const floatx4*)(h1 + (size_t)n*DMODEL);
  const floatx4* ya = (const floatx4*)(yslot + (size_t)sA*DMODEL);
  const floatx4* yb = (const floatx4*)(yslot + (size_t)sB*DMODEL);
  floatx4 v = a[t] + ya[t] + yb[t];
  ((floatx4*)(out + (size_t)n*DMODEL))[t] = v;
}

extern "C" void kernel_launch(void* const* d_in, const int* in_sizes, int n_in,
                              void* d_out, int out_size, void* d_ws, size_t ws_size,
                              hipStream_t stream) {
  const float* x      = (const float*)d_in[0];
  const float* qkv_w  = (const float*)d_in[1];
  const float* qkv_b  = (const float*)d_in[2];
  const float* out_w  = (const float*)d_in[3];
  const float* out_b  = (const float*)d_in[4];
  const float* ln1_w  = (const float*)d_in[5];
  const float* ln2_w  = (const float*)d_in[6];
  const float* gate_w = (const float*)d_in[7];
  const float* ew1    = (const float*)d_in[8];
  const float* eb1    = (const float*)d_in[9];
  const float* ew2    = (const float*)d_in[10];
  const float* eb2    = (const float*)d_in[11];
  const float* ew3    = (const float*)d_in[12];
  const float* eb3    = (const float*)d_in[13];
  float* out = (float*)d_out;

  // ---- workspace layout (max 84.3 MB; 96.1 MB proven safe) ----
  char* ws = (char*)d_ws;
  float* xn1f   = (float*)(ws + 0);          // 8 MB, live rmsnorm1..qkv
  float* attnof = (float*)(ws + 0);          // 8 MB, live attn..outproj (xn1f dead)
  float* qkvf   = (float*)(ws + 8388608);    // 24 MB, live qkv..rope
  float* h1     = (float*)(ws + 8388608);    // 8 MB, live outproj..end (qkvf dead)
  short* xn2    = (short*)(ws + 16777216);   // 4 MB, live rmsnorm2..moe13
  float* qrf    = (float*)(ws + 33554432);   // 8 MB, live rope..attn
  float* krf    = (float*)(ws + 41943040);   // 8 MB, live rope..attn
  float* vrf    = (float*)(ws + 50331648);   // 8 MB, live rope..attn
  short* hbuf   = (short*)(ws + 33554432);   // 32 MB, live moe13..moe2 (q/k/v dead)
  float* yslot  = (float*)(ws + 67108864);   // 16 MB, live moe2..combine
  float* cost         = (float*)(ws + 83886080);  // 128 KB
  float* sint         = (float*)(ws + 84017152);  // 128 KB
  float* probs        = (float*)(ws + 84148224);  //  64 KB
  int*   ctrl         = (int*)  (ws + 84213760);  //   1 KB
  int*   pair         = (int*)  (ws + 84214784);  //  16 KB
  float* gpair        = (float*)(ws + 84231168);  //  16 KB
  int*   slot_of_tok  = (int*)  (ws + 84247552);  //  16 KB
  int*   tok_of_slot  = (int*)  (ws + 84263936);  //  16 KB
  float* gate_of_slot = (float*)(ws + 84280320);  //  16 KB

  int* counts = ctrl;
  int* off    = ctrl + 8;
  int* cursor = ctrl + 20;

  hipMemsetAsync(ctrl, 0, 1024, stream);
  rope_table_kernel<<<T_SEQ, 32, 0, stream>>>(cost, sint);
  rmsnorm_f32_kernel<<<NTOK, 256, 0, stream>>>(x, ln1_w, xn1f);
  gemm_f32<0><<<dim3(48, 16), 256, 0, stream>>>(xn1f, qkv_w, qkv_b, nullptr, qkvf, 3072, DMODEL);
  rope_kernel<<<8192, 256, 0, stream>>>(qkvf, cost, sint, qrf, krf, vrf);
  attn_flash_kernel<<<dim3(32, 32), 256, 0, stream>>>(qrf, krf, vrf, attnof);
  gemm_f32<1><<<dim3(16, 16), 256, 0, stream>>>(attnof, out_w, out_b, x, h1, DMODEL, DMODEL);
  rmsnorm_bf16_kernel<<<NTOK, 256, 0, stream>>>(h1, ln2_w, xn2);
  gate_kernel<<<NTOK, 64, 0, stream>>>(h1, ln2_w, gate_w, probs, pair, gpair, counts);
  offsets_kernel<<<1, 64, 0, stream>>>(counts, off, cursor);
  scatter_kernel<<<8, 256, 0, stream>>>(pair, gpair, cursor, tok_of_slot, gate_of_slot, slot_of_tok);
  aux_kernel<<<1, 256, 0, stream>>>(probs, counts, out + 2097152);
  moe13_kernel<<<dim3(64, 16, 8), 256, 0, stream>>>(xn2, ew1, eb1, ew3, eb3, counts, off, tok_of_slot, hbuf);
  moe2_kernel<<<dim3(8, 16, 8), 256, 0, stream>>>(hbuf, ew2, eb2, counts, off, gate_of_slot, yslot);
  combine_kernel<<<NTOK, 256, 0, stream>>>(h1, yslot, slot_of_tok, out);
}